// Round 7
// baseline (559.685 us; speedup 1.0000x reference)
//
#include <hip/hip_runtime.h>

// GCN 2-layer forward, N=100000, E=3200000, 128->16->2.
// Round-7: round-5 base (passed, 249.6us) + bucket-LDS aggregation from
// round 6 (kills k_fillB per-dst sort). part-producing kernels (k_count,
// k_scatter w/ binary search, k_xw1) are byte-identical to round 5.
// k_bagg1/k_bagg2 accumulate per-bucket into LDS fp32 (stride 17/3) with
// shared-float atomicAdd; `s` clamped to [0,N) so corrupt part content
// shows up as absmax failure, never a memory fault.
// Algebra: hs = (x@W1)*dinv (bf16, 3.2MB, L2-resident);
//   h1[d]  = relu(dinv[d]*(sum_nbr hs + hs[d]) + b1), W2 fused -> h2s
//   out[d] = dinv[d]*(sum_nbr h2s + h2s[d]) + b2

#define EPB 8192     // edges per partition block

typedef unsigned int u32;
typedef unsigned short u16;

__device__ __forceinline__ float bflo(u32 u) { return __uint_as_float(u << 16); }
__device__ __forceinline__ float bfhi(u32 u) { return __uint_as_float(u & 0xffff0000u); }
__device__ __forceinline__ u32 pack_bf2(float a, float b) {   // RNE
    u32 ua = __float_as_uint(a); ua = (ua + 0x7fffu + ((ua >> 16) & 1u)) >> 16;
    u32 ub = __float_as_uint(b); ub = (ub + 0x7fffu + ((ub >> 16) & 1u)) >> 16;
    return ua | (ub << 16);
}

// ---------------- zero bucket counters ----------------
__global__ __launch_bounds__(512) void k_bzero(int* __restrict__ gcnt, int NBUK) {
    int t = threadIdx.x;
    if (t < NBUK) gcnt[t] = 0;
}

// ---------------- bucket histogram (round-5 verbatim) ----------------
__global__ __launch_bounds__(256) void k_count(const int* __restrict__ dst,
                                               int* __restrict__ gcnt,
                                               int E, int NBUK) {
    __shared__ int hist[512];
    int tid = threadIdx.x;
    for (int i = tid; i < NBUK; i += 256) hist[i] = 0;
    __syncthreads();
    int base = blockIdx.x * EPB;
    int end = base + EPB; if (end > E) end = E;
    for (int e = base + tid; e < end; e += 256)
        atomicAdd(&hist[dst[e] >> 8], 1);
    __syncthreads();
    for (int i = tid; i < NBUK; i += 256)
        if (hist[i]) atomicAdd(&gcnt[i], hist[i]);
}

// ---------------- scan bucket counts -> bases (single block) ----------------
__global__ __launch_bounds__(512) void k_bscan(const int* __restrict__ gcnt,
                                               int* __restrict__ gbase,
                                               int* __restrict__ gcur, int NBUK) {
    __shared__ int s[512];
    int tid = threadIdx.x;
    int v = (tid < NBUK) ? gcnt[tid] : 0;
    s[tid] = v;
    __syncthreads();
    for (int o = 1; o < 512; o <<= 1) {
        int t = (tid >= o) ? s[tid - o] : 0;
        __syncthreads();
        s[tid] += t;
        __syncthreads();
    }
    if (tid < NBUK) { int b = s[tid] - v; gbase[tid] = b; gcur[tid] = b; }
}

// ---------------- partition (round-5 verbatim, binary search) ----------------
__global__ __launch_bounds__(512) void k_scatter(const int* __restrict__ ei,
                                                 int* __restrict__ gcur,
                                                 u32* __restrict__ part,
                                                 int E, int NBUK) {
    __shared__ int hist[512];   // counts -> placement cursors
    __shared__ int lofs[512];   // local exclusive offsets (search key)
    __shared__ int rbase[512];  // global addr = rbase[b] + local slot j
    __shared__ u32 buf[EPB];
    int tid = threadIdx.x;
    hist[tid] = 0;
    __syncthreads();
    int base = blockIdx.x * EPB;
    int end = base + EPB; if (end > E) end = E;
    for (int e = base + tid; e < end; e += 512)
        atomicAdd(&hist[ei[E + e] >> 8], 1);
    __syncthreads();
    int v = hist[tid];
    lofs[tid] = v;
    __syncthreads();
    for (int o = 1; o < 512; o <<= 1) {
        int t = (tid >= o) ? lofs[tid - o] : 0;
        __syncthreads();
        lofs[tid] += t;
        __syncthreads();
    }
    int excl = lofs[tid] - v;
    int rb = 0;
    if (tid < NBUK && v > 0) rb = atomicAdd(&gcur[tid], v);  // reserve run
    __syncthreads();
    rbase[tid] = rb - excl;
    hist[tid] = excl;           // placement cursor
    lofs[tid] = excl;           // exclusive offsets for binary search
    __syncthreads();
    for (int e = base + tid; e < end; e += 512) {
        int s = ei[e], d = ei[E + e];
        int pos = atomicAdd(&hist[d >> 8], 1);
        buf[pos] = ((u32)(d & 255) << 24) | (u32)s;          // N < 2^24
    }
    __syncthreads();
    int cnt = end - base;
    for (int j = tid; j < cnt; j += 512) {
        int lo = 0, hi = NBUK - 1;                            // last b: lofs[b] <= j
        while (lo < hi) {
            int mid = (lo + hi + 1) >> 1;
            if (lofs[mid] <= j) lo = mid; else hi = mid - 1;
        }
        part[rbase[lo] + j] = buf[j];                         // ~coalesced runs
    }
}

// ---------------- per-dst degree -> dinv (per-bucket histogram) --------------
__global__ __launch_bounds__(256) void k_dinv(const u32* __restrict__ part,
                                              const int* __restrict__ gbase,
                                              const int* __restrict__ gcnt,
                                              float* __restrict__ dinv, int N) {
    __shared__ int hist[256];
    int b = blockIdx.x, tid = threadIdx.x;
    hist[tid] = 0;
    __syncthreads();
    int base = gbase[b], cnt = gcnt[b];
    for (int j = tid; j < cnt; j += 256)
        atomicAdd(&hist[part[base + j] >> 24], 1);
    __syncthreads();
    int d = b * 256 + tid;
    if (d < N) dinv[d] = rsqrtf((float)(hist[tid] + 1));      // +1 self loop
}

// ---------------- hs[N,16](bf16) = (x@W1)*dinv (round-5 verbatim) ------------
__global__ __launch_bounds__(256) void k_xw1(const float* __restrict__ x,
                                             const float* __restrict__ W1,
                                             const float* __restrict__ dinv,
                                             u16* __restrict__ hs, int N) {
    __shared__ float w[128 * 16];
    int tid = threadIdx.x;
    for (int i = tid; i < 2048; i += 256) w[i] = W1[i];
    __syncthreads();
    int t = blockIdx.x * 256 + tid;
    int n = t >> 2, q = t & 3;
    if (n >= N) return;
    const float4* xr = (const float4*)(x + (size_t)n * 128);
    const float4* w4 = (const float4*)w;    // w4[f*4+q] = W1[f][4q..4q+3]
    float ax = 0.f, ay = 0.f, az = 0.f, aw = 0.f;
    #pragma unroll
    for (int i = 0; i < 32; ++i) {
        float4 u = xr[i];
        int fb = i * 4;
        float4 wa = w4[(fb + 0) * 4 + q];
        float4 wb = w4[(fb + 1) * 4 + q];
        float4 wc = w4[(fb + 2) * 4 + q];
        float4 wd = w4[(fb + 3) * 4 + q];
        ax = fmaf(u.x, wa.x, ax); ay = fmaf(u.x, wa.y, ay);
        az = fmaf(u.x, wa.z, az); aw = fmaf(u.x, wa.w, aw);
        ax = fmaf(u.y, wb.x, ax); ay = fmaf(u.y, wb.y, ay);
        az = fmaf(u.y, wb.z, az); aw = fmaf(u.y, wb.w, aw);
        ax = fmaf(u.z, wc.x, ax); ay = fmaf(u.z, wc.y, ay);
        az = fmaf(u.z, wc.z, az); aw = fmaf(u.z, wc.w, aw);
        ax = fmaf(u.w, wd.x, ax); ay = fmaf(u.w, wd.y, ay);
        az = fmaf(u.w, wd.z, az); aw = fmaf(u.w, wd.w, aw);
    }
    float di = dinv[n];
    uint2 o;
    o.x = pack_bf2(ax * di, ay * di);
    o.y = pack_bf2(az * di, aw * di);
    ((uint2*)(hs + (size_t)n * 16))[q] = o;
}

// ---------------- layer-1 bucket aggregation + ReLU + W2 -> h2s --------------
// One block per bucket: LDS fp32 acc[256 dsts][16ch], stride 17 (bank spread).
// Pair of threads per edge (p = half-row parity, 8 channels each).
__global__ __launch_bounds__(512) void k_bagg1(const u32* __restrict__ part,
                                               const int* __restrict__ gbase,
                                               const int* __restrict__ gcnt,
                                               const u16* __restrict__ hs,
                                               const float* __restrict__ dinv,
                                               const float* __restrict__ W2,
                                               const float* __restrict__ b1,
                                               float* __restrict__ h2s, int N) {
    __shared__ float acc[256 * 17];
    __shared__ float w2s[32];
    __shared__ float b1s[16];
    int b = blockIdx.x, tid = threadIdx.x;
    for (int i = tid; i < 256 * 17; i += 512) acc[i] = 0.f;
    if (tid < 32) w2s[tid] = W2[tid];
    if (tid < 16) b1s[tid] = b1[tid];
    __syncthreads();
    int base = gbase[b], cnt = gcnt[b];
    int p = tid & 1;
    for (int j = (tid >> 1); j < cnt; j += 256) {
        u32 pv = part[base + j];
        int dl = pv >> 24;
        int s  = pv & 0xFFFFFF;
        if (s >= N) s = 0;                   // defensive: fault -> absmax fail
        uint4 u = ((const uint4*)(hs + (size_t)s * 16))[p];
        float* a = acc + dl * 17 + p * 8;
        atomicAdd(a + 0, bflo(u.x)); atomicAdd(a + 1, bfhi(u.x));
        atomicAdd(a + 2, bflo(u.y)); atomicAdd(a + 3, bfhi(u.y));
        atomicAdd(a + 4, bflo(u.z)); atomicAdd(a + 5, bfhi(u.z));
        atomicAdd(a + 6, bflo(u.w)); atomicAdd(a + 7, bfhi(u.w));
    }
    __syncthreads();
    int d = b * 256 + (tid >> 1);
    if (d < N) {
        float di = dinv[d];
        uint4 su = ((const uint4*)(hs + (size_t)d * 16))[p];  // self term
        float sf[8] = { bflo(su.x), bfhi(su.x), bflo(su.y), bfhi(su.y),
                        bflo(su.z), bfhi(su.z), bflo(su.w), bfhi(su.w) };
        const float* av = acc + (tid >> 1) * 17 + p * 8;
        float p0 = 0.f, p1 = 0.f;
        #pragma unroll
        for (int k = 0; k < 8; ++k) {
            int c = p * 8 + k;
            float v = fmaxf(fmaf(di, av[k] + sf[k], b1s[c]), 0.f);
            p0 = fmaf(v, w2s[2 * c],     p0);
            p1 = fmaf(v, w2s[2 * c + 1], p1);
        }
        p0 += __shfl_xor(p0, 1);
        p1 += __shfl_xor(p1, 1);
        if (p == 0)
            *(float2*)(h2s + (size_t)d * 2) = make_float2(p0 * di, p1 * di);
    }
}

// ---------------- layer-2 bucket aggregation -> out ----------------
__global__ __launch_bounds__(512) void k_bagg2(const u32* __restrict__ part,
                                               const int* __restrict__ gbase,
                                               const int* __restrict__ gcnt,
                                               const float* __restrict__ h2s,
                                               const float* __restrict__ dinv,
                                               const float* __restrict__ b2,
                                               float* __restrict__ out, int N) {
    __shared__ float acc[256 * 3];     // stride 3: bank spread
    __shared__ float b2s[2];
    int b = blockIdx.x, tid = threadIdx.x;
    for (int i = tid; i < 768; i += 512) acc[i] = 0.f;
    if (tid < 2) b2s[tid] = b2[tid];
    __syncthreads();
    int base = gbase[b], cnt = gcnt[b];
    for (int j = tid; j < cnt; j += 512) {
        u32 pv = part[base + j];
        int dl = pv >> 24;
        int s  = pv & 0xFFFFFF;
        if (s >= N) s = 0;                   // defensive
        float2 v = *(const float2*)(h2s + (size_t)s * 2);
        atomicAdd(&acc[dl * 3 + 0], v.x);
        atomicAdd(&acc[dl * 3 + 1], v.y);
    }
    __syncthreads();
    int d = b * 256 + (tid >> 1), c = tid & 1;
    if (d < N) {
        float di = dinv[d];
        float sv = h2s[(size_t)d * 2 + c];
        out[(size_t)d * 2 + c] =
            fmaf(di, acc[(tid >> 1) * 3 + c] + sv, b2s[c]);
    }
}

extern "C" void kernel_launch(void* const* d_in, const int* in_sizes, int n_in,
                              void* d_out, int out_size, void* d_ws, size_t ws_size,
                              hipStream_t stream) {
    const float* x  = (const float*)d_in[0];
    const int*   ei = (const int*)d_in[1];
    const float* W1 = (const float*)d_in[2];
    const float* b1 = (const float*)d_in[3];
    const float* W2 = (const float*)d_in[4];
    const float* b2 = (const float*)d_in[5];
    float* out = (float*)d_out;

    const int N = in_sizes[0] / 128;      // 100000
    const int E = in_sizes[1] / 2;        // 3200000
    const int NBUK = (N + 255) / 256;     // 391 (<= 512)
    const int NPB  = (E + EPB - 1) / EPB; // 391

    char* ws = (char*)d_ws;
    size_t off = 0;
    auto alloc = [&](size_t bytes) {
        void* p = ws + off;
        off = (off + bytes + 255) & ~(size_t)255;
        return p;
    };
    u32*   part  = (u32*)alloc((size_t)E * 4);       // bucket-grouped edges
    float* dinv  = (float*)alloc((size_t)N * 4);
    u16*   hs    = (u16*)alloc((size_t)N * 16 * 2);  // bf16
    float* h2s   = (float*)alloc((size_t)N * 2 * 4);
    int*   gcnt  = (int*)alloc((size_t)NBUK * 4);
    int*   gbase = (int*)alloc((size_t)NBUK * 4);
    int*   gcur  = (int*)alloc((size_t)NBUK * 4);

    k_bzero  <<<dim3(1),    dim3(512), 0, stream>>>(gcnt, NBUK);
    k_count  <<<dim3(NPB),  dim3(256), 0, stream>>>(ei + E, gcnt, E, NBUK);
    k_bscan  <<<dim3(1),    dim3(512), 0, stream>>>(gcnt, gbase, gcur, NBUK);
    k_scatter<<<dim3(NPB),  dim3(512), 0, stream>>>(ei, gcur, part, E, NBUK);
    k_dinv   <<<dim3(NBUK), dim3(256), 0, stream>>>(part, gbase, gcnt, dinv, N);
    k_xw1    <<<dim3((N * 4 + 255) / 256), dim3(256), 0, stream>>>(x, W1, dinv, hs, N);
    k_bagg1  <<<dim3(NBUK), dim3(512), 0, stream>>>(part, gbase, gcnt, hs, dinv, W2, b1, h2s, N);
    k_bagg2  <<<dim3(NBUK), dim3(512), 0, stream>>>(part, gbase, gcnt, h2s, dinv, b2, out, N);
}

// Round 8
// 227.786 us; speedup vs baseline: 2.4571x; 2.4571x over previous
//
#include <hip/hip_runtime.h>

// GCN 2-layer forward, N=100000, E=3200000, 128->16->2.
// Round-8: round-5 structure (validated, 249.6us) with three upgrades:
//  - k_xw1: K-split over 4 lanes/node, x read ONCE (round-5 read it 4x =
//    205 MB); LDS W1 sections padded to 516 floats (q*516 -> disjoint banks).
//  - k_agg1h2: 4 nodes/wave (16 lanes: 4 lanes/row x 4 edge groups) --
//    round-5 profile showed per-node fixed cost ~ edge-loop cost at deg~33.
//  - k_agg2: 4 nodes/wave, 16 lanes/node.
// CSR build (k_count/k_bscan/k_scatter/k_fillB) is round-5 verbatim.
// Round-7 lesson: per-bucket ds_add aggregation = 8x slower than sorted
// gather (343us, LDS-atomic serialization @ 24% occupancy). Don't go back.
// Algebra: hs = (x@W1)*dinv (bf16, 3.2MB, L2-resident);
//   h1[d]  = relu(dinv[d]*(sum_nbr hs + hs[d]) + b1), W2 fused -> h2s
//   out[d] = dinv[d]*(sum_nbr h2s + h2s[d]) + b2

#define EPB 8192     // edges per partition block
#define CAP 16384    // LDS slots per bucket in k_fillB

typedef unsigned int u32;
typedef unsigned short u16;

__device__ __forceinline__ float bflo(u32 u) { return __uint_as_float(u << 16); }
__device__ __forceinline__ float bfhi(u32 u) { return __uint_as_float(u & 0xffff0000u); }
__device__ __forceinline__ u32 pack_bf2(float a, float b) {   // RNE
    u32 ua = __float_as_uint(a); ua = (ua + 0x7fffu + ((ua >> 16) & 1u)) >> 16;
    u32 ub = __float_as_uint(b); ub = (ub + 0x7fffu + ((ub >> 16) & 1u)) >> 16;
    return ua | (ub << 16);
}

// ---------------- zero bucket counters ----------------
__global__ __launch_bounds__(512) void k_bzero(int* __restrict__ gcnt, int NBUK) {
    int t = threadIdx.x;
    if (t < NBUK) gcnt[t] = 0;
}

// ---------------- bucket histogram (round-5 verbatim) ----------------
__global__ __launch_bounds__(256) void k_count(const int* __restrict__ dst,
                                               int* __restrict__ gcnt,
                                               int E, int NBUK) {
    __shared__ int hist[512];
    int tid = threadIdx.x;
    for (int i = tid; i < NBUK; i += 256) hist[i] = 0;
    __syncthreads();
    int base = blockIdx.x * EPB;
    int end = base + EPB; if (end > E) end = E;
    for (int e = base + tid; e < end; e += 256)
        atomicAdd(&hist[dst[e] >> 8], 1);
    __syncthreads();
    for (int i = tid; i < NBUK; i += 256)
        if (hist[i]) atomicAdd(&gcnt[i], hist[i]);
}

// ---------------- scan bucket counts -> bases (round-5 verbatim) -------------
__global__ __launch_bounds__(512) void k_bscan(const int* __restrict__ gcnt,
                                               int* __restrict__ gbase,
                                               int* __restrict__ gcur,
                                               int* __restrict__ rp,
                                               int N, int E, int NBUK) {
    __shared__ int s[512];
    int tid = threadIdx.x;
    int v = (tid < NBUK) ? gcnt[tid] : 0;
    s[tid] = v;
    __syncthreads();
    for (int o = 1; o < 512; o <<= 1) {
        int t = (tid >= o) ? s[tid - o] : 0;
        __syncthreads();
        s[tid] += t;
        __syncthreads();
    }
    if (tid < NBUK) { int b = s[tid] - v; gbase[tid] = b; gcur[tid] = b; }
    if (tid == 0) rp[N] = E;
}

// ---------------- partition (round-5 verbatim, binary search) ----------------
__global__ __launch_bounds__(512) void k_scatter(const int* __restrict__ ei,
                                                 int* __restrict__ gcur,
                                                 u32* __restrict__ part,
                                                 int E, int NBUK) {
    __shared__ int hist[512];   // counts -> placement cursors
    __shared__ int lofs[512];   // local exclusive offsets (search key)
    __shared__ int rbase[512];  // global addr = rbase[b] + local slot j
    __shared__ u32 buf[EPB];
    int tid = threadIdx.x;
    hist[tid] = 0;
    __syncthreads();
    int base = blockIdx.x * EPB;
    int end = base + EPB; if (end > E) end = E;
    for (int e = base + tid; e < end; e += 512)
        atomicAdd(&hist[ei[E + e] >> 8], 1);
    __syncthreads();
    int v = hist[tid];
    lofs[tid] = v;
    __syncthreads();
    for (int o = 1; o < 512; o <<= 1) {
        int t = (tid >= o) ? lofs[tid - o] : 0;
        __syncthreads();
        lofs[tid] += t;
        __syncthreads();
    }
    int excl = lofs[tid] - v;
    int rb = 0;
    if (tid < NBUK && v > 0) rb = atomicAdd(&gcur[tid], v);  // reserve run
    __syncthreads();
    rbase[tid] = rb - excl;
    hist[tid] = excl;           // placement cursor
    lofs[tid] = excl;           // exclusive offsets for binary search
    __syncthreads();
    for (int e = base + tid; e < end; e += 512) {
        int s = ei[e], d = ei[E + e];
        int pos = atomicAdd(&hist[d >> 8], 1);
        buf[pos] = ((u32)(d & 255) << 24) | (u32)s;          // N < 2^24
    }
    __syncthreads();
    int cnt = end - base;
    for (int j = tid; j < cnt; j += 512) {
        int lo = 0, hi = NBUK - 1;                            // last b: lofs[b] <= j
        while (lo < hi) {
            int mid = (lo + hi + 1) >> 1;
            if (lofs[mid] <= j) lo = mid; else hi = mid - 1;
        }
        part[rbase[lo] + j] = buf[j];                         // ~coalesced runs
    }
}

// ---------------- per-bucket sort by dst (round-5 verbatim) ------------------
__global__ __launch_bounds__(256) void k_fillB(u32* __restrict__ part,
                                               const int* __restrict__ gbase,
                                               const int* __restrict__ gcnt,
                                               int* __restrict__ rp,
                                               float* __restrict__ dinv, int N) {
    __shared__ int hist[256];
    __shared__ int ofs[256];
    __shared__ u32 srcbuf[CAP];
    int b = blockIdx.x, tid = threadIdx.x;
    int base = gbase[b], cnt = gcnt[b];
    hist[tid] = 0;
    __syncthreads();
    for (int j = tid; j < cnt; j += 256)
        atomicAdd(&hist[part[base + j] >> 24], 1);
    __syncthreads();
    int v = hist[tid];                 // deg of dst (b*256 + tid)
    ofs[tid] = v;
    __syncthreads();
    for (int o = 1; o < 256; o <<= 1) {
        int t = (tid >= o) ? ofs[tid - o] : 0;
        __syncthreads();
        ofs[tid] += t;
        __syncthreads();
    }
    int excl = ofs[tid] - v;
    hist[tid] = excl;                  // scatter cursor
    __syncthreads();
    for (int j = tid; j < cnt; j += 256) {
        u32 pv = part[base + j];
        int pos = atomicAdd(&hist[pv >> 24], 1);
        if (pos < CAP) srcbuf[pos] = pv & 0xFFFFFFu;
    }
    __syncthreads();
    for (int j = tid; j < cnt; j += 256)
        part[base + j] = srcbuf[j];    // coalesced write-back
    int d = b * 256 + tid;
    if (d < N) {
        rp[d] = base + excl;
        dinv[d] = rsqrtf((float)(v + 1));   // +1 self loop
    }
}

// ---------------- hs[N,16](bf16) = (x@W1)*dinv, K-split, x read once ---------
// 4 lanes/node, lane q covers K rows [32q,32q+32); butterfly over lanes 1,2.
__global__ __launch_bounds__(256) void k_xw1(const float* __restrict__ x,
                                             const float* __restrict__ W1,
                                             const float* __restrict__ dinv,
                                             u16* __restrict__ hs, int N) {
    __shared__ float w[4 * 516];   // section q = W1 rows 32q..32q+31; +4 pad
    int tid = threadIdx.x;
    for (int t = tid; t < 2048; t += 256)
        w[(t >> 9) * 516 + (t & 511)] = W1[t];
    __syncthreads();
    int t = blockIdx.x * 256 + tid;
    int n = t >> 2, q = t & 3;
    if (n >= N) return;
    const float4* xr = (const float4*)(x + (size_t)n * 128 + q * 32);  // 8 f4
    const float* ws = w + q * 516;      // 516 floats = 2064 B, 16B-aligned
    float acc[16];
    #pragma unroll
    for (int c = 0; c < 16; ++c) acc[c] = 0.f;
    #pragma unroll
    for (int i = 0; i < 8; ++i) {
        float4 u = xr[i];
        const float4* wf = (const float4*)(ws + i * 64);  // rows 4i..4i+3
        #pragma unroll
        for (int c4 = 0; c4 < 4; ++c4) {
            float4 wa = wf[c4];        // row 4i+0, channels 4c4..4c4+3
            float4 wb = wf[4 + c4];    // row 4i+1
            float4 wc = wf[8 + c4];    // row 4i+2
            float4 wd = wf[12 + c4];   // row 4i+3
            int c = c4 * 4;
            acc[c+0] = fmaf(u.x, wa.x, acc[c+0]); acc[c+1] = fmaf(u.x, wa.y, acc[c+1]);
            acc[c+2] = fmaf(u.x, wa.z, acc[c+2]); acc[c+3] = fmaf(u.x, wa.w, acc[c+3]);
            acc[c+0] = fmaf(u.y, wb.x, acc[c+0]); acc[c+1] = fmaf(u.y, wb.y, acc[c+1]);
            acc[c+2] = fmaf(u.y, wb.z, acc[c+2]); acc[c+3] = fmaf(u.y, wb.w, acc[c+3]);
            acc[c+0] = fmaf(u.z, wc.x, acc[c+0]); acc[c+1] = fmaf(u.z, wc.y, acc[c+1]);
            acc[c+2] = fmaf(u.z, wc.z, acc[c+2]); acc[c+3] = fmaf(u.z, wc.w, acc[c+3]);
            acc[c+0] = fmaf(u.w, wd.x, acc[c+0]); acc[c+1] = fmaf(u.w, wd.y, acc[c+1]);
            acc[c+2] = fmaf(u.w, wd.z, acc[c+2]); acc[c+3] = fmaf(u.w, wd.w, acc[c+3]);
        }
    }
    #pragma unroll
    for (int c = 0; c < 16; ++c) {
        acc[c] += __shfl_xor(acc[c], 1);
        acc[c] += __shfl_xor(acc[c], 2);
    }
    float di = dinv[n];
    uint2 o;
    o.x = pack_bf2(acc[4*q+0] * di, acc[4*q+1] * di);
    o.y = pack_bf2(acc[4*q+2] * di, acc[4*q+3] * di);
    ((uint2*)(hs + (size_t)n * 16))[q] = o;
}

// ---------------- fused layer-1 gather + ReLU + W2 projection ----------------
// 4 nodes/wave; 16 lanes/node = 4 lanes/row (uint2 each) x 4 edge groups.
__global__ __launch_bounds__(256) void k_agg1h2(const int* __restrict__ rp,
                                                const int* __restrict__ csr,
                                                const u16* __restrict__ hs,
                                                const float* __restrict__ dinv,
                                                const float* __restrict__ W2,
                                                const float* __restrict__ b1,
                                                float* __restrict__ h2s, int N) {
    int lane = threadIdx.x & 63;
    int wid = blockIdx.x * 16 + (threadIdx.x >> 6) * 4 + (lane >> 4);
    if (wid >= N) return;
    int l = lane & 15;
    int c4 = l & 3, g = l >> 2;                    // channel quad, edge group
    int beg = rp[wid], end = rp[wid + 1];
    float ax = 0.f, ay = 0.f, az = 0.f, aw = 0.f;
    for (int j = beg + g; j < end; j += 4) {
        int s = csr[j];
        uint2 u = ((const uint2*)(hs + (size_t)s * 16))[c4];
        ax += bflo(u.x); ay += bfhi(u.x);
        az += bflo(u.y); aw += bfhi(u.y);
    }
    // reduce over the 4 edge groups (lane bits 2,3 within the 16-lane segment)
    ax += __shfl_xor(ax, 4); ay += __shfl_xor(ay, 4);
    az += __shfl_xor(az, 4); aw += __shfl_xor(aw, 4);
    ax += __shfl_xor(ax, 8); ay += __shfl_xor(ay, 8);
    az += __shfl_xor(az, 8); aw += __shfl_xor(aw, 8);
    uint2 su = ((const uint2*)(hs + (size_t)wid * 16))[c4];   // self term
    ax += bflo(su.x); ay += bfhi(su.x);
    az += bflo(su.y); aw += bfhi(su.y);
    float di = dinv[wid];
    float4 bq = ((const float4*)b1)[c4];
    float vx = fmaxf(fmaf(di, ax, bq.x), 0.f);
    float vy = fmaxf(fmaf(di, ay, bq.y), 0.f);
    float vz = fmaxf(fmaf(di, az, bq.z), 0.f);
    float vw = fmaxf(fmaf(di, aw, bq.w), 0.f);
    // W2[16,2] row-major: float4 pair covers channels 4c4..4c4+3, both cols
    float4 pa = ((const float4*)W2)[2 * c4];
    float4 pb = ((const float4*)W2)[2 * c4 + 1];
    float p0 = vx * pa.x + vy * pa.z + vz * pb.x + vw * pb.z;
    float p1 = vx * pa.y + vy * pa.w + vz * pb.y + vw * pb.w;
    p0 += __shfl_xor(p0, 1); p1 += __shfl_xor(p1, 1);
    p0 += __shfl_xor(p0, 2); p1 += __shfl_xor(p1, 2);
    if (l == 0)
        *(float2*)(h2s + (size_t)wid * 2) = make_float2(p0 * di, p1 * di);
}

// ---------------- layer-2 gather -> out (4 nodes/wave, 16 lanes/node) --------
__global__ __launch_bounds__(256) void k_agg2(const int* __restrict__ rp,
                                              const int* __restrict__ csr,
                                              const float* __restrict__ h2s,
                                              const float* __restrict__ dinv,
                                              const float* __restrict__ b2,
                                              float* __restrict__ out, int N) {
    int lane = threadIdx.x & 63;
    int wid = blockIdx.x * 16 + (threadIdx.x >> 6) * 4 + (lane >> 4);
    if (wid >= N) return;
    int l = lane & 15;
    int beg = rp[wid], end = rp[wid + 1];
    float a0 = 0.f, a1 = 0.f;
    for (int j = beg + l; j < end; j += 16) {
        int s = csr[j];
        float2 v = *(const float2*)(h2s + (size_t)s * 2);
        a0 += v.x; a1 += v.y;
    }
    a0 += __shfl_xor(a0, 1); a1 += __shfl_xor(a1, 1);
    a0 += __shfl_xor(a0, 2); a1 += __shfl_xor(a1, 2);
    a0 += __shfl_xor(a0, 4); a1 += __shfl_xor(a1, 4);
    a0 += __shfl_xor(a0, 8); a1 += __shfl_xor(a1, 8);
    if (l == 0) {
        float di = dinv[wid];
        float2 sv = *(const float2*)(h2s + (size_t)wid * 2);
        *(float2*)(out + (size_t)wid * 2) =
            make_float2(fmaf(di, a0 + sv.x, b2[0]), fmaf(di, a1 + sv.y, b2[1]));
    }
}

extern "C" void kernel_launch(void* const* d_in, const int* in_sizes, int n_in,
                              void* d_out, int out_size, void* d_ws, size_t ws_size,
                              hipStream_t stream) {
    const float* x  = (const float*)d_in[0];
    const int*   ei = (const int*)d_in[1];
    const float* W1 = (const float*)d_in[2];
    const float* b1 = (const float*)d_in[3];
    const float* W2 = (const float*)d_in[4];
    const float* b2 = (const float*)d_in[5];
    float* out = (float*)d_out;

    const int N = in_sizes[0] / 128;      // 100000
    const int E = in_sizes[1] / 2;        // 3200000
    const int NBUK = (N + 255) / 256;     // 391 (<= 512)
    const int NPB  = (E + EPB - 1) / EPB; // 391

    char* ws = (char*)d_ws;
    size_t off = 0;
    auto alloc = [&](size_t bytes) {
        void* p = ws + off;
        off = (off + bytes + 255) & ~(size_t)255;
        return p;
    };
    u32*   part  = (u32*)alloc((size_t)E * 4);       // partition buf == csr
    int*   rp    = (int*)alloc((size_t)(N + 1) * 4);
    float* dinv  = (float*)alloc((size_t)N * 4);
    u16*   hs    = (u16*)alloc((size_t)N * 16 * 2);  // bf16
    float* h2s   = (float*)alloc((size_t)N * 2 * 4);
    int*   gcnt  = (int*)alloc((size_t)NBUK * 4);
    int*   gbase = (int*)alloc((size_t)NBUK * 4);
    int*   gcur  = (int*)alloc((size_t)NBUK * 4);

    k_bzero  <<<dim3(1),    dim3(512), 0, stream>>>(gcnt, NBUK);
    k_count  <<<dim3(NPB),  dim3(256), 0, stream>>>(ei + E, gcnt, E, NBUK);
    k_bscan  <<<dim3(1),    dim3(512), 0, stream>>>(gcnt, gbase, gcur, rp, N, E, NBUK);
    k_scatter<<<dim3(NPB),  dim3(512), 0, stream>>>(ei, gcur, part, E, NBUK);
    k_fillB  <<<dim3(NBUK), dim3(256), 0, stream>>>(part, gbase, gcnt, rp, dinv, N);
    k_xw1    <<<dim3((N * 4 + 255) / 256), dim3(256), 0, stream>>>(x, W1, dinv, hs, N);
    k_agg1h2 <<<dim3((N + 15) / 16), dim3(256), 0, stream>>>(rp, (const int*)part, hs, dinv, W2, b1, h2s, N);
    k_agg2   <<<dim3((N + 15) / 16), dim3(256), 0, stream>>>(rp, (const int*)part, h2s, dinv, b2, out, N);
}

// Round 10
// 215.648 us; speedup vs baseline: 2.5954x; 1.0563x over previous
//
#include <hip/hip_runtime.h>

// GCN 2-layer forward, N=100000, E=3200000, 128->16->2.
// Round-10 == round-9 resubmitted verbatim (round-9 bench was an infra
// failure: "MI355X container failed twice" -- code never ran).
// Round-9 changes vs round-8 (227.8us, all kernels <40us):
//  - k_count persists per-block bucket histograms (bhist u16); k_scatter
//    loads its row instead of re-reading 12.8MB of dst + 3.2M LDS atomics.
//  - k_fillB/k_count at 512 threads (serial depth 32->16 iters).
// Validated and kept: binary-search writeback in k_scatter (r6 bmap variant
// faulted), K-split k_xw1, 4-nodes/wave agg kernels, bf16 hs (3.2MB,
// L2-resident). Round-7 lesson: LDS-atomic aggregation is 8x worse than
// sorted gather -- don't revisit.
// Algebra: hs = (x@W1)*dinv;
//   h1[d]  = relu(dinv[d]*(sum_nbr hs + hs[d]) + b1), W2 fused -> h2s
//   out[d] = dinv[d]*(sum_nbr h2s + h2s[d]) + b2

#define EPB 8192     // edges per partition block
#define CAP 16384    // LDS slots per bucket in k_fillB (mean 8192, 90 sigma)

typedef unsigned int u32;
typedef unsigned short u16;

__device__ __forceinline__ float bflo(u32 u) { return __uint_as_float(u << 16); }
__device__ __forceinline__ float bfhi(u32 u) { return __uint_as_float(u & 0xffff0000u); }
__device__ __forceinline__ u32 pack_bf2(float a, float b) {   // RNE
    u32 ua = __float_as_uint(a); ua = (ua + 0x7fffu + ((ua >> 16) & 1u)) >> 16;
    u32 ub = __float_as_uint(b); ub = (ub + 0x7fffu + ((ub >> 16) & 1u)) >> 16;
    return ua | (ub << 16);
}

// ---------------- zero bucket counters ----------------
__global__ __launch_bounds__(512) void k_bzero(int* __restrict__ gcnt, int NBUK) {
    int t = threadIdx.x;
    if (t < NBUK) gcnt[t] = 0;
}

// ---------------- bucket histogram; persists per-block rows ----------------
__global__ __launch_bounds__(512) void k_count(const int* __restrict__ dst,
                                               int* __restrict__ gcnt,
                                               u16* __restrict__ bhist,
                                               int E, int NBUK) {
    __shared__ int hist[512];
    int tid = threadIdx.x;
    hist[tid] = 0;
    __syncthreads();
    int base = blockIdx.x * EPB;
    int end = base + EPB; if (end > E) end = E;
    for (int e = base + tid; e < end; e += 512)
        atomicAdd(&hist[dst[e] >> 8], 1);
    __syncthreads();
    int v = hist[tid];
    if (tid < NBUK) {
        if (v) atomicAdd(&gcnt[tid], v);
        bhist[(size_t)blockIdx.x * 512 + tid] = (u16)v;   // row for k_scatter
    }
}

// ---------------- scan bucket counts -> bases (single block) ----------------
__global__ __launch_bounds__(512) void k_bscan(const int* __restrict__ gcnt,
                                               int* __restrict__ gbase,
                                               int* __restrict__ gcur,
                                               int* __restrict__ rp,
                                               int N, int E, int NBUK) {
    __shared__ int s[512];
    int tid = threadIdx.x;
    int v = (tid < NBUK) ? gcnt[tid] : 0;
    s[tid] = v;
    __syncthreads();
    for (int o = 1; o < 512; o <<= 1) {
        int t = (tid >= o) ? s[tid - o] : 0;
        __syncthreads();
        s[tid] += t;
        __syncthreads();
    }
    if (tid < NBUK) { int b = s[tid] - v; gbase[tid] = b; gcur[tid] = b; }
    if (tid == 0) rp[N] = E;
}

// ---------------- partition; histogram loaded from bhist ----------------
__global__ __launch_bounds__(512) void k_scatter(const int* __restrict__ ei,
                                                 const u16* __restrict__ bhist,
                                                 int* __restrict__ gcur,
                                                 u32* __restrict__ part,
                                                 int E, int NBUK) {
    __shared__ int hist[512];   // placement cursors
    __shared__ int lofs[512];   // exclusive offsets (binary-search key)
    __shared__ int rbase[512];  // global addr = rbase[b] + local slot j
    __shared__ u32 buf[EPB];
    int tid = threadIdx.x;
    int v = (tid < NBUK) ? (int)bhist[(size_t)blockIdx.x * 512 + tid] : 0;
    lofs[tid] = v;
    __syncthreads();
    for (int o = 1; o < 512; o <<= 1) {
        int t = (tid >= o) ? lofs[tid - o] : 0;
        __syncthreads();
        lofs[tid] += t;
        __syncthreads();
    }
    int excl = lofs[tid] - v;
    int rb = 0;
    if (tid < NBUK && v > 0) rb = atomicAdd(&gcur[tid], v);  // reserve run
    rbase[tid] = rb - excl;
    hist[tid] = excl;           // placement cursor
    lofs[tid] = excl;           // overwrite scan values with excl (own slot)
    __syncthreads();
    int base = blockIdx.x * EPB;
    int end = base + EPB; if (end > E) end = E;
    for (int e = base + tid; e < end; e += 512) {
        int s = ei[e], d = ei[E + e];
        int pos = atomicAdd(&hist[d >> 8], 1);
        buf[pos] = ((u32)(d & 255) << 24) | (u32)s;          // N < 2^24
    }
    __syncthreads();
    int cnt = end - base;
    for (int j = tid; j < cnt; j += 512) {
        int lo = 0, hi = NBUK - 1;                            // last b: lofs[b] <= j
        while (lo < hi) {
            int mid = (lo + hi + 1) >> 1;
            if (lofs[mid] <= j) lo = mid; else hi = mid - 1;
        }
        part[rbase[lo] + j] = buf[j];                         // ~coalesced runs
    }
}

// ---------------- per-bucket sort by dst; csr in place (512 thr) -------------
__global__ __launch_bounds__(512) void k_fillB(u32* __restrict__ part,
                                               const int* __restrict__ gbase,
                                               const int* __restrict__ gcnt,
                                               int* __restrict__ rp,
                                               float* __restrict__ dinv, int N) {
    __shared__ int hist[256];
    __shared__ int ofs[256];
    __shared__ u32 srcbuf[CAP];
    int b = blockIdx.x, tid = threadIdx.x;
    int base = gbase[b], cnt = gcnt[b];
    if (tid < 256) hist[tid] = 0;
    __syncthreads();
    for (int j = tid; j < cnt; j += 512)
        atomicAdd(&hist[part[base + j] >> 24], 1);
    __syncthreads();
    int v = 0;
    if (tid < 256) { v = hist[tid]; ofs[tid] = v; }
    __syncthreads();
    for (int o = 1; o < 256; o <<= 1) {
        int t = 0;
        if (tid < 256 && tid >= o) t = ofs[tid - o];
        __syncthreads();
        if (tid < 256) ofs[tid] += t;
        __syncthreads();
    }
    int excl = 0;
    if (tid < 256) { excl = ofs[tid] - v; hist[tid] = excl; }
    __syncthreads();
    for (int j = tid; j < cnt; j += 512) {
        u32 pv = part[base + j];
        int pos = atomicAdd(&hist[pv >> 24], 1);
        if (pos < CAP) srcbuf[pos] = pv & 0xFFFFFFu;
    }
    __syncthreads();
    for (int j = tid; j < cnt; j += 512)
        part[base + j] = srcbuf[j];    // coalesced write-back
    int d = b * 256 + tid;
    if (tid < 256 && d < N) {
        rp[d] = base + excl;
        dinv[d] = rsqrtf((float)(v + 1));   // +1 self loop
    }
}

// ---------------- hs[N,16](bf16) = (x@W1)*dinv, K-split, x read once ---------
__global__ __launch_bounds__(256) void k_xw1(const float* __restrict__ x,
                                             const float* __restrict__ W1,
                                             const float* __restrict__ dinv,
                                             u16* __restrict__ hs, int N) {
    __shared__ float w[4 * 516];   // section q = W1 rows 32q..32q+31; +4 pad
    int tid = threadIdx.x;
    for (int t = tid; t < 2048; t += 256)
        w[(t >> 9) * 516 + (t & 511)] = W1[t];
    __syncthreads();
    int t = blockIdx.x * 256 + tid;
    int n = t >> 2, q = t & 3;
    if (n >= N) return;
    const float4* xr = (const float4*)(x + (size_t)n * 128 + q * 32);  // 8 f4
    const float* ws = w + q * 516;
    float acc[16];
    #pragma unroll
    for (int c = 0; c < 16; ++c) acc[c] = 0.f;
    #pragma unroll
    for (int i = 0; i < 8; ++i) {
        float4 u = xr[i];
        const float4* wf = (const float4*)(ws + i * 64);  // rows 4i..4i+3
        #pragma unroll
        for (int c4 = 0; c4 < 4; ++c4) {
            float4 wa = wf[c4];
            float4 wb = wf[4 + c4];
            float4 wc = wf[8 + c4];
            float4 wd = wf[12 + c4];
            int c = c4 * 4;
            acc[c+0] = fmaf(u.x, wa.x, acc[c+0]); acc[c+1] = fmaf(u.x, wa.y, acc[c+1]);
            acc[c+2] = fmaf(u.x, wa.z, acc[c+2]); acc[c+3] = fmaf(u.x, wa.w, acc[c+3]);
            acc[c+0] = fmaf(u.y, wb.x, acc[c+0]); acc[c+1] = fmaf(u.y, wb.y, acc[c+1]);
            acc[c+2] = fmaf(u.y, wb.z, acc[c+2]); acc[c+3] = fmaf(u.y, wb.w, acc[c+3]);
            acc[c+0] = fmaf(u.z, wc.x, acc[c+0]); acc[c+1] = fmaf(u.z, wc.y, acc[c+1]);
            acc[c+2] = fmaf(u.z, wc.z, acc[c+2]); acc[c+3] = fmaf(u.z, wc.w, acc[c+3]);
            acc[c+0] = fmaf(u.w, wd.x, acc[c+0]); acc[c+1] = fmaf(u.w, wd.y, acc[c+1]);
            acc[c+2] = fmaf(u.w, wd.z, acc[c+2]); acc[c+3] = fmaf(u.w, wd.w, acc[c+3]);
        }
    }
    #pragma unroll
    for (int c = 0; c < 16; ++c) {
        acc[c] += __shfl_xor(acc[c], 1);
        acc[c] += __shfl_xor(acc[c], 2);
    }
    float di = dinv[n];
    uint2 o;
    o.x = pack_bf2(acc[4*q+0] * di, acc[4*q+1] * di);
    o.y = pack_bf2(acc[4*q+2] * di, acc[4*q+3] * di);
    ((uint2*)(hs + (size_t)n * 16))[q] = o;
}

// ---------------- fused layer-1 gather + ReLU + W2 projection ----------------
// 4 nodes/wave; 16 lanes/node = 4 lanes/row (uint2 each) x 4 edge groups.
__global__ __launch_bounds__(256) void k_agg1h2(const int* __restrict__ rp,
                                                const int* __restrict__ csr,
                                                const u16* __restrict__ hs,
                                                const float* __restrict__ dinv,
                                                const float* __restrict__ W2,
                                                const float* __restrict__ b1,
                                                float* __restrict__ h2s, int N) {
    int lane = threadIdx.x & 63;
    int wid = blockIdx.x * 16 + (threadIdx.x >> 6) * 4 + (lane >> 4);
    if (wid >= N) return;
    int l = lane & 15;
    int c4 = l & 3, g = l >> 2;                    // channel quad, edge group
    int beg = rp[wid], end = rp[wid + 1];
    float ax = 0.f, ay = 0.f, az = 0.f, aw = 0.f;
    for (int j = beg + g; j < end; j += 4) {
        int s = csr[j];
        uint2 u = ((const uint2*)(hs + (size_t)s * 16))[c4];
        ax += bflo(u.x); ay += bfhi(u.x);
        az += bflo(u.y); aw += bfhi(u.y);
    }
    ax += __shfl_xor(ax, 4); ay += __shfl_xor(ay, 4);
    az += __shfl_xor(az, 4); aw += __shfl_xor(aw, 4);
    ax += __shfl_xor(ax, 8); ay += __shfl_xor(ay, 8);
    az += __shfl_xor(az, 8); aw += __shfl_xor(aw, 8);
    uint2 su = ((const uint2*)(hs + (size_t)wid * 16))[c4];   // self term
    ax += bflo(su.x); ay += bfhi(su.x);
    az += bflo(su.y); aw += bfhi(su.y);
    float di = dinv[wid];
    float4 bq = ((const float4*)b1)[c4];
    float vx = fmaxf(fmaf(di, ax, bq.x), 0.f);
    float vy = fmaxf(fmaf(di, ay, bq.y), 0.f);
    float vz = fmaxf(fmaf(di, az, bq.z), 0.f);
    float vw = fmaxf(fmaf(di, aw, bq.w), 0.f);
    float4 pa = ((const float4*)W2)[2 * c4];
    float4 pb = ((const float4*)W2)[2 * c4 + 1];
    float p0 = vx * pa.x + vy * pa.z + vz * pb.x + vw * pb.z;
    float p1 = vx * pa.y + vy * pa.w + vz * pb.y + vw * pb.w;
    p0 += __shfl_xor(p0, 1); p1 += __shfl_xor(p1, 1);
    p0 += __shfl_xor(p0, 2); p1 += __shfl_xor(p1, 2);
    if (l == 0)
        *(float2*)(h2s + (size_t)wid * 2) = make_float2(p0 * di, p1 * di);
}

// ---------------- layer-2 gather -> out (4 nodes/wave, 16 lanes/node) --------
__global__ __launch_bounds__(256) void k_agg2(const int* __restrict__ rp,
                                              const int* __restrict__ csr,
                                              const float* __restrict__ h2s,
                                              const float* __restrict__ dinv,
                                              const float* __restrict__ b2,
                                              float* __restrict__ out, int N) {
    int lane = threadIdx.x & 63;
    int wid = blockIdx.x * 16 + (threadIdx.x >> 6) * 4 + (lane >> 4);
    if (wid >= N) return;
    int l = lane & 15;
    int beg = rp[wid], end = rp[wid + 1];
    float a0 = 0.f, a1 = 0.f;
    for (int j = beg + l; j < end; j += 16) {
        int s = csr[j];
        float2 v = *(const float2*)(h2s + (size_t)s * 2);
        a0 += v.x; a1 += v.y;
    }
    a0 += __shfl_xor(a0, 1); a1 += __shfl_xor(a1, 1);
    a0 += __shfl_xor(a0, 2); a1 += __shfl_xor(a1, 2);
    a0 += __shfl_xor(a0, 4); a1 += __shfl_xor(a1, 4);
    a0 += __shfl_xor(a0, 8); a1 += __shfl_xor(a1, 8);
    if (l == 0) {
        float di = dinv[wid];
        float2 sv = *(const float2*)(h2s + (size_t)wid * 2);
        *(float2*)(out + (size_t)wid * 2) =
            make_float2(fmaf(di, a0 + sv.x, b2[0]), fmaf(di, a1 + sv.y, b2[1]));
    }
}

extern "C" void kernel_launch(void* const* d_in, const int* in_sizes, int n_in,
                              void* d_out, int out_size, void* d_ws, size_t ws_size,
                              hipStream_t stream) {
    const float* x  = (const float*)d_in[0];
    const int*   ei = (const int*)d_in[1];
    const float* W1 = (const float*)d_in[2];
    const float* b1 = (const float*)d_in[3];
    const float* W2 = (const float*)d_in[4];
    const float* b2 = (const float*)d_in[5];
    float* out = (float*)d_out;

    const int N = in_sizes[0] / 128;      // 100000
    const int E = in_sizes[1] / 2;        // 3200000
    const int NBUK = (N + 255) / 256;     // 391 (<= 512)
    const int NPB  = (E + EPB - 1) / EPB; // 391

    char* ws = (char*)d_ws;
    size_t off = 0;
    auto alloc = [&](size_t bytes) {
        void* p = ws + off;
        off = (off + bytes + 255) & ~(size_t)255;
        return p;
    };
    u32*   part  = (u32*)alloc((size_t)E * 4);       // partition buf == csr
    int*   rp    = (int*)alloc((size_t)(N + 1) * 4);
    float* dinv  = (float*)alloc((size_t)N * 4);
    u16*   hs    = (u16*)alloc((size_t)N * 16 * 2);  // bf16
    float* h2s   = (float*)alloc((size_t)N * 2 * 4);
    int*   gcnt  = (int*)alloc((size_t)NBUK * 4);
    int*   gbase = (int*)alloc((size_t)NBUK * 4);
    int*   gcur  = (int*)alloc((size_t)NBUK * 4);
    u16*   bhist = (u16*)alloc((size_t)NPB * 512 * 2);

    k_bzero  <<<dim3(1),    dim3(512), 0, stream>>>(gcnt, NBUK);
    k_count  <<<dim3(NPB),  dim3(512), 0, stream>>>(ei + E, gcnt, bhist, E, NBUK);
    k_bscan  <<<dim3(1),    dim3(512), 0, stream>>>(gcnt, gbase, gcur, rp, N, E, NBUK);
    k_scatter<<<dim3(NPB),  dim3(512), 0, stream>>>(ei, bhist, gcur, part, E, NBUK);
    k_fillB  <<<dim3(NBUK), dim3(512), 0, stream>>>(part, gbase, gcnt, rp, dinv, N);
    k_xw1    <<<dim3((N * 4 + 255) / 256), dim3(256), 0, stream>>>(x, W1, dinv, hs, N);
    k_agg1h2 <<<dim3((N + 15) / 16), dim3(256), 0, stream>>>(rp, (const int*)part, hs, dinv, W2, b1, h2s, N);
    k_agg2   <<<dim3((N + 15) / 16), dim3(256), 0, stream>>>(rp, (const int*)part, h2s, dinv, b2, out, N);
}